// Round 1
// baseline (181.705 us; speedup 1.0000x reference)
//
#include <hip/hip_runtime.h>

// Problem constants (match reference setup_inputs)
#define NEXP  64
#define NTOK  32768
#define TOPK  2
#define NFLAT (NTOK * TOPK)   // 65536 flattened routing entries
#define DM    1024            // d_model
#define NBLK  256             // blocks for hist/scatter
#define EPB   (NFLAT / NBLK)  // 256 elements per block (== blockDim)

// Output layout (all float32, concatenated flat in return order):
//   [0, O1)   sorted_and_dispatched  (NFLAT x DM)
//   [O1, O2)  inverse_permute_mapping (NFLAT)
//   [O2, O3)  expert_sort_indices     (NFLAT)  == identity
//   [O3, ...) num_tokens_per_expert   (NEXP)
#define O1 ((size_t)NFLAT * DM)
#define O2 (O1 + NFLAT)
#define O3 (O2 + NFLAT)

// ws layout (ints):
//   [0]                  stride flag (1 if routing is int32, 2 if int64 words)
//   [64, 64+NBLK*NEXP)   blockCounts
//   [64+NBLK*NEXP, ...)  blockOffset (NBLK*NEXP)
//   then dstOf (NFLAT)
#define WS_FLAG   0
#define WS_BC     64
#define WS_BO     (WS_BC + NBLK * NEXP)
#define WS_DST    (WS_BO + NBLK * NEXP)

// Detect whether routing buffer is int64 (odd 32-bit words all zero) or int32.
// Reads only the first NFLAT words (valid under both layouts).
__global__ void k_detect(const int* __restrict__ routing, int* __restrict__ ws) {
    __shared__ int any;
    if (threadIdx.x == 0) any = 0;
    __syncthreads();
    int local = 0;
    // odd word indices: 1,3,...,NFLAT-1  -> NFLAT/2 = 32768 of them
    for (int k = threadIdx.x; k < NFLAT / 2; k += blockDim.x) {
        local |= routing[2 * k + 1];
    }
    if (local) atomicOr(&any, 1);
    __syncthreads();
    if (threadIdx.x == 0) ws[WS_FLAG] = any ? 1 : 2;  // nonzero odd words -> int32
}

__global__ void k_hist(const int* __restrict__ routing, int* __restrict__ ws) {
    __shared__ int h[NEXP];
    const int stride = ws[WS_FLAG];
    int t = threadIdx.x;
    if (t < NEXP) h[t] = 0;
    __syncthreads();
    int i = blockIdx.x * EPB + t;
    int e = routing[(size_t)i * stride];
    atomicAdd(&h[e], 1);
    __syncthreads();
    if (t < NEXP) ws[WS_BC + blockIdx.x * NEXP + t] = h[t];
}

// One block, 64 threads: per-expert running offsets across blocks + expert base scan.
__global__ void k_offsets(int* __restrict__ ws, float* __restrict__ outCounts) {
    __shared__ int tot[NEXP];
    __shared__ int start[NEXP];
    int e = threadIdx.x;
    if (e < NEXP) {
        int run = 0;
        for (int b = 0; b < NBLK; ++b) {
            ws[WS_BO + b * NEXP + e] = run;
            run += ws[WS_BC + b * NEXP + e];
        }
        tot[e] = run;
    }
    __syncthreads();
    if (e == 0) {
        int acc = 0;
        for (int x = 0; x < NEXP; ++x) { start[x] = acc; acc += tot[x]; }
    }
    __syncthreads();
    if (e < NEXP) {
        int s = start[e];
        for (int b = 0; b < NBLK; ++b) ws[WS_BO + b * NEXP + e] += s;
        outCounts[e] = (float)tot[e];
    }
}

// Stable scatter: dst = blockOffset[b][e] + rank_within_block.
__global__ void k_scatter(const int* __restrict__ routing, int* __restrict__ ws,
                          float* __restrict__ outInv, float* __restrict__ outESI) {
    __shared__ int se[EPB];
    const int stride = ws[WS_FLAG];
    int t = threadIdx.x;
    int i = blockIdx.x * EPB + t;
    int e = routing[(size_t)i * stride];
    se[t] = e;
    __syncthreads();
    int rank = 0;
    for (int j = 0; j < t; ++j) rank += (se[j] == e) ? 1 : 0;
    int dst = ws[WS_BO + blockIdx.x * NEXP + e] + rank;
    ws[WS_DST + i] = dst;
    outInv[dst] = (float)i;   // sorted_idx[dst] = i
    outESI[i]  = (float)i;    // identity permutation
}

// Copy: one block per token, read row once, write to its two destinations.
__global__ void k_copy(const float* __restrict__ hidden, const int* __restrict__ ws,
                       float* __restrict__ out) {
    int tok = blockIdx.x;          // 0..NTOK-1
    int t = threadIdx.x;           // 256 threads, 1 float4 each
    const float4* src = (const float4*)(hidden + (size_t)tok * DM);
    float4 v = src[t];
    int d0 = ws[WS_DST + 2 * tok];
    int d1 = ws[WS_DST + 2 * tok + 1];
    ((float4*)(out + (size_t)d0 * DM))[t] = v;
    ((float4*)(out + (size_t)d1 * DM))[t] = v;
}

extern "C" void kernel_launch(void* const* d_in, const int* in_sizes, int n_in,
                              void* d_out, int out_size, void* d_ws, size_t ws_size,
                              hipStream_t stream) {
    const float* hidden = (const float*)d_in[0];
    const int* routing = (const int*)d_in[1];
    float* out = (float*)d_out;
    int* ws = (int*)d_ws;

    k_detect<<<1, 256, 0, stream>>>(routing, ws);
    k_hist<<<NBLK, EPB, 0, stream>>>(routing, ws);
    k_offsets<<<1, 64, 0, stream>>>(ws, out + O3);
    k_scatter<<<NBLK, EPB, 0, stream>>>(routing, ws, out + O1, out + O2);
    k_copy<<<NTOK, 256, 0, stream>>>(hidden, ws, out);
}

// Round 3
// 100.037 us; speedup vs baseline: 1.8164x; 1.8164x over previous
//
#include <hip/hip_runtime.h>

#define NEXP  64
#define NTOK  32768
#define TOPK  2
#define NFLAT (NTOK * TOPK)   // 65536
#define DM    1024
#define NBLK  256
#define EPB   (NFLAT / NBLK)  // 256

typedef float v4f __attribute__((ext_vector_type(4)));

// Output layout (float32, concatenated):
#define O1 ((size_t)NFLAT * DM)
#define O2 (O1 + NFLAT)
#define O3 (O2 + NFLAT)

// ws layout (ints)
#define WS_FLAG   0
#define WS_BC     64
#define WS_BO     (WS_BC + NBLK * NEXP)
#define WS_DST    (WS_BO + NBLK * NEXP)

// Detect int64 vs int32 routing layout. Reads only words [0, NFLAT) (safe
// under both layouts). int64 -> odd words (hi halves of elems 0..32767) all 0.
__global__ void k_detect(const int4* __restrict__ routing4, int* __restrict__ ws) {
    __shared__ int any;
    if (threadIdx.x == 0) any = 0;
    __syncthreads();
    int acc = 0;
    for (int k = threadIdx.x; k < NFLAT / 4; k += 1024) {
        int4 w = routing4[k];
        acc |= w.y | w.w;
    }
    if (acc) atomicOr(&any, 1);
    __syncthreads();
    if (threadIdx.x == 0) ws[WS_FLAG] = any ? 1 : 2;
}

__global__ void k_hist(const int* __restrict__ routing, int* __restrict__ ws) {
    __shared__ int h[NEXP];
    const int stride = ws[WS_FLAG];
    int t = threadIdx.x;
    if (t < NEXP) h[t] = 0;
    __syncthreads();
    int i = blockIdx.x * EPB + t;
    int e = routing[(size_t)i * stride];
    atomicAdd(&h[e], 1);
    __syncthreads();
    if (t < NEXP) ws[WS_BC + blockIdx.x * NEXP + t] = h[t];
}

// 256 threads = 4 waves; wave c owns blocks [c*64,(c+1)*64), lane = expert.
__global__ void k_offsets(int* __restrict__ ws, float* __restrict__ outCounts) {
    __shared__ int partial[4][NEXP];
    __shared__ int chunkbase[4][NEXP];
    __shared__ int startLds[NEXP];
    int t = threadIdx.x;
    int e = t & 63, c = t >> 6;
    int sum = 0;
    #pragma unroll 8
    for (int b = c * 64; b < (c + 1) * 64; ++b) sum += ws[WS_BC + b * NEXP + e];
    partial[c][e] = sum;
    __syncthreads();
    if (c == 0) {
        int p0 = partial[0][e], p1 = partial[1][e], p2 = partial[2][e], p3 = partial[3][e];
        int tot = p0 + p1 + p2 + p3;
        chunkbase[0][e] = 0; chunkbase[1][e] = p0;
        chunkbase[2][e] = p0 + p1; chunkbase[3][e] = p0 + p1 + p2;
        int x = tot;
        for (int d = 1; d < 64; d <<= 1) {
            int y = __shfl_up(x, d, 64);
            if (e >= d) x += y;
        }
        startLds[e] = x - tot;  // exclusive prefix
        outCounts[e] = (float)tot;
    }
    __syncthreads();
    int run = startLds[e] + chunkbase[c][e];
    #pragma unroll 8
    for (int b = c * 64; b < (c + 1) * 64; ++b) {
        ws[WS_BO + b * NEXP + e] = run;
        run += ws[WS_BC + b * NEXP + e];
    }
}

// Stable scatter: dst = blockOffset[b][e] + rank_within_block.
__global__ void k_scatter(const int* __restrict__ routing, int* __restrict__ ws,
                          float* __restrict__ outInv, float* __restrict__ outESI) {
    __shared__ int se[EPB];
    const int stride = ws[WS_FLAG];
    int t = threadIdx.x;
    int i = blockIdx.x * EPB + t;
    int e = routing[(size_t)i * stride];
    se[t] = e;
    __syncthreads();
    int rank = 0;
    for (int j = 0; j < t; ++j) rank += (se[j] == e) ? 1 : 0;
    int dst = ws[WS_BO + blockIdx.x * NEXP + e] + rank;
    ws[WS_DST + i] = dst;
    outInv[dst] = (float)i;
    outESI[i]  = (float)i;
}

// One block per token; nontemporal streaming (no reuse on either side).
__global__ void k_copy(const float* __restrict__ hidden, const int* __restrict__ ws,
                       float* __restrict__ out) {
    int tok = blockIdx.x;
    int t = threadIdx.x;
    const v4f* src = (const v4f*)(hidden + (size_t)tok * DM);
    v4f v = __builtin_nontemporal_load(src + t);
    int d0 = ws[WS_DST + 2 * tok];
    int d1 = ws[WS_DST + 2 * tok + 1];
    __builtin_nontemporal_store(v, (v4f*)(out + (size_t)d0 * DM) + t);
    __builtin_nontemporal_store(v, (v4f*)(out + (size_t)d1 * DM) + t);
}

extern "C" void kernel_launch(void* const* d_in, const int* in_sizes, int n_in,
                              void* d_out, int out_size, void* d_ws, size_t ws_size,
                              hipStream_t stream) {
    const float* hidden = (const float*)d_in[0];
    const int* routing = (const int*)d_in[1];
    float* out = (float*)d_out;
    int* ws = (int*)d_ws;

    k_detect<<<1, 1024, 0, stream>>>((const int4*)routing, ws);
    k_hist<<<NBLK, EPB, 0, stream>>>(routing, ws);
    k_offsets<<<1, 256, 0, stream>>>(ws, out + O3);
    k_scatter<<<NBLK, EPB, 0, stream>>>(routing, ws, out + O1, out + O2);
    k_copy<<<NTOK, 256, 0, stream>>>(hidden, ws, out);
}

// Round 4
// 99.873 us; speedup vs baseline: 1.8194x; 1.0016x over previous
//
#include <hip/hip_runtime.h>

#define NEXP  64
#define NTOK  32768
#define TOPK  2
#define NFLAT (NTOK * TOPK)   // 65536
#define DM    1024
#define NBLK  256
#define EPB   (NFLAT / NBLK)  // 256
#define DETBLK 64

typedef float v4f __attribute__((ext_vector_type(4)));

// Output layout (float32, concatenated):
#define O1 ((size_t)NFLAT * DM)
#define O2 (O1 + NFLAT)
#define O3 (O2 + NFLAT)

// ws layout (ints)
#define WS_DET    0                      // DETBLK per-block OR slots
#define WS_BC     (WS_DET + DETBLK)      // NBLK*NEXP block counts
#define WS_BO     (WS_BC + NBLK * NEXP)  // NBLK*NEXP block offsets
#define WS_DST    (WS_BO + NBLK * NEXP)  // NFLAT destinations

// Detect int64 vs int32 routing layout. Reads only words [0, NFLAT) (safe
// under both layouts). int64 -> odd words (hi halves of elems 0..32767) all 0.
// Each block writes its OR unconditionally to a private slot (no init needed).
__global__ void k_detect(const int4* __restrict__ routing4, int* __restrict__ ws) {
    __shared__ int o;
    int t = threadIdx.x;
    if (t == 0) o = 0;
    __syncthreads();
    // NFLAT/4 = 16384 int4 words; 64 blocks * 256 threads = 1 each
    int k = blockIdx.x * 256 + t;
    int4 w = routing4[k];
    int acc = w.y | w.w;
    if (__any(acc != 0)) { if ((t & 63) == 0) atomicOr(&o, 1); }
    __syncthreads();
    if (t == 0) ws[WS_DET + blockIdx.x] = o;
}

// Reduce the DETBLK detect slots to a stride (1=int32, 2=int64 words).
__device__ __forceinline__ int get_stride(const int* ws) {
    __shared__ int strideSh;
    int t = threadIdx.x;
    if (t < 64) {
        int v = ws[WS_DET + t];  // DETBLK == 64, wave 0
        unsigned long long b = __ballot(v != 0);
        if (t == 0) strideSh = b ? 1 : 2;
    }
    __syncthreads();
    return strideSh;
}

__global__ void k_hist(const int* __restrict__ routing, int* __restrict__ ws) {
    __shared__ int h[NEXP];
    int t = threadIdx.x;
    const int stride = get_stride(ws);
    if (t < NEXP) h[t] = 0;
    __syncthreads();
    int i = blockIdx.x * EPB + t;
    int e = routing[(size_t)i * stride];
    atomicAdd(&h[e], 1);
    __syncthreads();
    if (t < NEXP) ws[WS_BC + blockIdx.x * NEXP + t] = h[t];
}

// 256 threads = 4 waves; wave c owns blocks [c*64,(c+1)*64), lane = expert.
__global__ void k_offsets(int* __restrict__ ws, float* __restrict__ outCounts) {
    __shared__ int partial[4][NEXP];
    __shared__ int chunkbase[4][NEXP];
    __shared__ int startLds[NEXP];
    int t = threadIdx.x;
    int e = t & 63, c = t >> 6;
    int sum = 0;
    #pragma unroll 8
    for (int b = c * 64; b < (c + 1) * 64; ++b) sum += ws[WS_BC + b * NEXP + e];
    partial[c][e] = sum;
    __syncthreads();
    if (c == 0) {
        int p0 = partial[0][e], p1 = partial[1][e], p2 = partial[2][e], p3 = partial[3][e];
        int tot = p0 + p1 + p2 + p3;
        chunkbase[0][e] = 0; chunkbase[1][e] = p0;
        chunkbase[2][e] = p0 + p1; chunkbase[3][e] = p0 + p1 + p2;
        int x = tot;
        for (int d = 1; d < 64; d <<= 1) {
            int y = __shfl_up(x, d, 64);
            if (e >= d) x += y;
        }
        startLds[e] = x - tot;  // exclusive prefix
        outCounts[e] = (float)tot;
    }
    __syncthreads();
    int run = startLds[e] + chunkbase[c][e];
    #pragma unroll 8
    for (int b = c * 64; b < (c + 1) * 64; ++b) {
        ws[WS_BO + b * NEXP + e] = run;
        run += ws[WS_BC + b * NEXP + e];
    }
}

// Stable scatter: dst = blockOffset[b][e] + rank_within_block.
__global__ void k_scatter(const int* __restrict__ routing, int* __restrict__ ws,
                          float* __restrict__ outInv, float* __restrict__ outESI) {
    __shared__ int se[EPB];
    int t = threadIdx.x;
    const int stride = get_stride(ws);
    int i = blockIdx.x * EPB + t;
    int e = routing[(size_t)i * stride];
    se[t] = e;
    __syncthreads();
    int rank = 0;
    for (int j = 0; j < t; ++j) rank += (se[j] == e) ? 1 : 0;
    int dst = ws[WS_BO + blockIdx.x * NEXP + e] + rank;
    ws[WS_DST + i] = dst;
    outInv[dst] = (float)i;
    outESI[i]  = (float)i;
}

// Grid-stride copy: 2048 blocks x 16 tokens each; nontemporal both sides.
__global__ void k_copy(const float* __restrict__ hidden, const int* __restrict__ ws,
                       float* __restrict__ out) {
    int t = threadIdx.x;
    for (int tok = blockIdx.x; tok < NTOK; tok += gridDim.x) {
        const v4f* src = (const v4f*)(hidden + (size_t)tok * DM);
        v4f v = __builtin_nontemporal_load(src + t);
        int d0 = ws[WS_DST + 2 * tok];
        int d1 = ws[WS_DST + 2 * tok + 1];
        __builtin_nontemporal_store(v, (v4f*)(out + (size_t)d0 * DM) + t);
        __builtin_nontemporal_store(v, (v4f*)(out + (size_t)d1 * DM) + t);
    }
}

extern "C" void kernel_launch(void* const* d_in, const int* in_sizes, int n_in,
                              void* d_out, int out_size, void* d_ws, size_t ws_size,
                              hipStream_t stream) {
    const float* hidden = (const float*)d_in[0];
    const int* routing = (const int*)d_in[1];
    float* out = (float*)d_out;
    int* ws = (int*)d_ws;

    k_detect<<<DETBLK, 256, 0, stream>>>((const int4*)routing, ws);
    k_hist<<<NBLK, EPB, 0, stream>>>(routing, ws);
    k_offsets<<<1, 256, 0, stream>>>(ws, out + O3);
    k_scatter<<<NBLK, EPB, 0, stream>>>(routing, ws, out + O1, out + O2);
    k_copy<<<2048, 256, 0, stream>>>(hidden, ws, out);
}